// Round 3
// baseline (723.234 us; speedup 1.0000x reference)
//
#include <hip/hip_runtime.h>
#include <hip/hip_bf16.h>
#include <math.h>

// attr = labels(1024x50000 f32) @ weight(50000x300 f32); out = attr/(||attr||+1e-7)
// k1: weight -> Wt[n][k] bf16 (n padded to 320) -- LDS transpose
// k2: split-K MFMA GEMM, BM=64 BN=320 BK=64 (round-0 proven loop), with
//     (a) unpadded BKP=64 + XOR-swizzled LDS (T2)  -> 48 KB -> 3 blocks/CU
//     (b) SPLIT=49 (grid 784 = 3.06 blocks/CU) for latency-hiding TLP
// k3: reduce partials over splits + row L2 normalize (fused)
typedef __bf16 bf16;
typedef bf16 bf16x8 __attribute__((ext_vector_type(8)));
typedef float f32x4 __attribute__((ext_vector_type(4)));

constexpr int Mdim = 1024;
constexpr int Kdim = 50000;
constexpr int Ndim = 300;
constexpr int NP   = 320;

constexpr int BM = 64, BN = 320, BK = 64;
constexpr int MT = Mdim / BM;      // 16 m-tiles
constexpr int ROWB = BK * 2;       // 128 B per LDS row (no pad; swizzled)

__device__ __forceinline__ bf16x8 bzero8() {
    bf16x8 v;
#pragma unroll
    for (int e = 0; e < 8; ++e) v[e] = (bf16)0.0f;
    return v;
}

// XOR swizzle: row-major [row][BK] bf16, byte_off ^= (row&7)<<4.
// All accesses are 16B-aligned; XOR flips bits 4..6 only -> stays aligned.
__device__ __forceinline__ bf16* swz(bf16* base, int row, int colByte) {
    return (bf16*)((char*)base + row * ROWB + (colByte ^ ((row & 7) << 4)));
}
__device__ __forceinline__ const bf16* swz(const bf16* base, int row, int colByte) {
    return (const bf16*)((const char*)base + row * ROWB + (colByte ^ ((row & 7) << 4)));
}

// ---------------- k1: transpose + convert -----------------------------------
constexpr int TK = 64;
constexpr int TS = 301;
__global__ __launch_bounds__(256) void transpose_w(const float* __restrict__ W,
                                                   bf16* __restrict__ Wt)
{
    __shared__ bf16 tile[TK * TS];
    const int k0 = blockIdx.x * TK;
    const int t  = threadIdx.x;

    for (int c = t; c < 64 * 75; c += 256) {
        const int kk = c / 75;
        const int ch = c % 75;
        const int k  = k0 + kk;
        float4 v = make_float4(0.f, 0.f, 0.f, 0.f);
        if (k < Kdim) v = *(const float4*)(W + (size_t)k * Ndim + ch * 4);
        bf16* p = &tile[kk * TS + ch * 4];
        p[0] = (bf16)v.x; p[1] = (bf16)v.y; p[2] = (bf16)v.z; p[3] = (bf16)v.w;
    }
    __syncthreads();
    for (int c = t; c < NP * 8; c += 256) {
        const int n  = c >> 3;
        const int ch = c & 7;
        const int k  = k0 + ch * 8;
        if (k + 8 <= Kdim) {
            bf16x8 v = bzero8();
            if (n < Ndim) {
#pragma unroll
                for (int j = 0; j < 8; ++j) v[j] = tile[(ch * 8 + j) * TS + n];
            }
            *(bf16x8*)(Wt + (size_t)n * Kdim + k) = v;
        }
    }
}

// ---------------- k2: split-K MFMA GEMM (round-0 loop + swizzle + 3blk) -----
// ATOMIC=false: out = P, partials at P[ks][Mdim][NP] (plain stores)
// ATOMIC=true : out = Cacc[Mdim][NP] (atomicAdd), Cacc pre-zeroed
template<int SPLIT, int SEGLEN, bool ATOMIC>
__global__ __launch_bounds__(512, 6) void gemm_kernel(const float* __restrict__ A,
                                                      const bf16* __restrict__ Wt,
                                                      float* __restrict__ out)
{
    __shared__ bf16 As[BM * BK];   //  8192 B
    __shared__ bf16 Bs[BN * BK];   // 40960 B  (49152 total -> 3 blocks/CU)

    const int bx   = blockIdx.x;
    const int mt   = bx & (MT - 1);
    const int ks   = bx >> 4;
    const int m0   = mt * BM;
    const int kbeg = ks * SEGLEN;
    const int kend = min(kbeg + SEGLEN, Kdim);

    const int t    = threadIdx.x;
    const int lane = t & 63;
    const int wave = t >> 6;         // 0..7 as 2m x 4n
    const int wm   = wave >> 2;
    const int wn   = wave & 3;
    const int lm   = lane & 15;
    const int lq   = lane >> 4;      // 0..3

    const int arow = t >> 3;
    const int acol = (t & 7) * 8;    // elements
    const float* aptr = A + (size_t)(m0 + arow) * Kdim;

    float4 af[2];
    bf16x8 bfr[5];

    auto load_tiles = [&](int k0) {
        const int k = k0 + acol;
        if (k + 8 <= kend) {
            af[0] = *(const float4*)(aptr + k);
            af[1] = *(const float4*)(aptr + k + 4);
        } else {
            af[0] = make_float4(0.f, 0.f, 0.f, 0.f);
            af[1] = make_float4(0.f, 0.f, 0.f, 0.f);
        }
#pragma unroll
        for (int i = 0; i < 5; ++i) {
            const int c = t + 512 * i;
            const int brow = c >> 3;
            const int bcol = (c & 7) * 8;
            const int kk = k0 + bcol;
            bfr[i] = (kk + 8 <= kend) ? *(const bf16x8*)(Wt + (size_t)brow * Kdim + kk)
                                      : bzero8();
        }
    };
    auto store_tiles = [&]() {
        bf16x8 v;
        v[0]=(bf16)af[0].x; v[1]=(bf16)af[0].y; v[2]=(bf16)af[0].z; v[3]=(bf16)af[0].w;
        v[4]=(bf16)af[1].x; v[5]=(bf16)af[1].y; v[6]=(bf16)af[1].z; v[7]=(bf16)af[1].w;
        *(bf16x8*)swz(As, arow, acol * 2) = v;
#pragma unroll
        for (int i = 0; i < 5; ++i) {
            const int c = t + 512 * i;
            const int brow = c >> 3;
            const int bcol = (c & 7) * 8;
            *(bf16x8*)swz(Bs, brow, bcol * 2) = bfr[i];
        }
    };

    f32x4 acc[2][5] = {};

    load_tiles(kbeg);
    for (int k0 = kbeg; k0 < kend; k0 += BK) {
        store_tiles();
        __syncthreads();
        if (k0 + BK < kend) load_tiles(k0 + BK);
#pragma unroll
        for (int s = 0; s < 2; ++s) {
            bf16x8 a[2], b[5];
#pragma unroll
            for (int i = 0; i < 2; ++i)
                a[i] = *(const bf16x8*)swz(As, wm * 32 + i * 16 + lm, s * 64 + lq * 16);
#pragma unroll
            for (int j = 0; j < 5; ++j)
                b[j] = *(const bf16x8*)swz(Bs, wn * 80 + j * 16 + lm, s * 64 + lq * 16);
#pragma unroll
            for (int i = 0; i < 2; ++i)
#pragma unroll
                for (int j = 0; j < 5; ++j)
                    acc[i][j] = __builtin_amdgcn_mfma_f32_16x16x32_bf16(a[i], b[j], acc[i][j], 0, 0, 0);
        }
        __syncthreads();
    }

    // C/D layout: col=lane&15, row=(lane>>4)*4+r  [learn_hip m89]
    const int col0 = wn * 80 + lm;
    const int rloc = wm * 32 + lq * 4;
    if (ATOMIC) {
#pragma unroll
        for (int i = 0; i < 2; ++i)
#pragma unroll
            for (int j = 0; j < 5; ++j)
#pragma unroll
                for (int r = 0; r < 4; ++r)
                    atomicAdd(&out[(size_t)(m0 + rloc + i * 16 + r) * NP + col0 + j * 16],
                              acc[i][j][r]);
    } else {
        float* P = out + (size_t)ks * Mdim * NP;
#pragma unroll
        for (int i = 0; i < 2; ++i)
#pragma unroll
            for (int j = 0; j < 5; ++j)
#pragma unroll
                for (int r = 0; r < 4; ++r)
                    P[(size_t)(m0 + rloc + i * 16 + r) * NP + col0 + j * 16] = acc[i][j][r];
    }
}

// ---------------- k3a: reduce partials + L2 normalize (partial path) --------
__global__ __launch_bounds__(320) void reduce_norm_k(const float* __restrict__ P,
                                                     float* __restrict__ out,
                                                     int split)
{
    const int b = blockIdx.x;
    const int t = threadIdx.x;
    float v = 0.f;
    for (int ks = 0; ks < split; ++ks)
        v += P[((size_t)ks * Mdim + b) * NP + t];     // coalesced per ks
    float ss = v * v;
#pragma unroll
    for (int o = 32; o > 0; o >>= 1) ss += __shfl_down(ss, o, 64);
    __shared__ float wsum[5];
    __shared__ float scale;
    if ((t & 63) == 0) wsum[t >> 6] = ss;
    __syncthreads();
    if (t == 0) {
        float s = wsum[0] + wsum[1] + wsum[2] + wsum[3] + wsum[4];
        scale = 1.0f / (sqrtf(s) + 1e-7f);
    }
    __syncthreads();
    if (t < Ndim) out[(size_t)b * Ndim + t] = v * scale;
}

// ---------------- k3b: normalize only (atomic fallback path) ----------------
__global__ __launch_bounds__(320) void normalize_k(const float* __restrict__ Cacc,
                                                   float* __restrict__ out)
{
    const int b = blockIdx.x;
    const int t = threadIdx.x;
    float v = 0.f;
    if (t < Ndim) v = Cacc[(size_t)b * NP + t];
    float ss = v * v;
#pragma unroll
    for (int o = 32; o > 0; o >>= 1) ss += __shfl_down(ss, o, 64);
    __shared__ float wsum[5];
    __shared__ float scale;
    if ((t & 63) == 0) wsum[t >> 6] = ss;
    __syncthreads();
    if (t == 0) {
        float s = wsum[0] + wsum[1] + wsum[2] + wsum[3] + wsum[4];
        scale = 1.0f / (sqrtf(s) + 1e-7f);
    }
    __syncthreads();
    if (t < Ndim) out[(size_t)b * Ndim + t] = v * scale;
}

// ---------------- launch ----------------------------------------------------
extern "C" void kernel_launch(void* const* d_in, const int* in_sizes, int n_in,
                              void* d_out, int out_size, void* d_ws, size_t ws_size,
                              hipStream_t stream)
{
    const float* labels = (const float*)d_in[0];   // 1024 x 50000
    const float* weight = (const float*)d_in[1];   // 50000 x 300
    float* out = (float*)d_out;                    // 1024 x 300

    bf16* Wt = (bf16*)d_ws;                                   // 32.0 MB at offset 0
    const size_t wtBytes  = (size_t)NP * Kdim * sizeof(bf16); // 32,000,000
    float* aux = (float*)((char*)d_ws + wtBytes);
    const size_t perSplit = (size_t)Mdim * NP * sizeof(float); // 1.31 MB

    transpose_w<<<dim3((Kdim + TK - 1) / TK), dim3(256), 0, stream>>>(weight, Wt);

    if (ws_size >= wtBytes + 49 * perSplit) {
        // partial path, SPLIT=49 (SEGLEN=1024 = 16 x BK, grid 784 = 3.06 blk/CU)
        gemm_kernel<49, 1024, false><<<dim3(MT * 49), dim3(512), 0, stream>>>(labels, Wt, aux);
        reduce_norm_k<<<dim3(Mdim), dim3(320), 0, stream>>>(aux, out, 49);
    } else if (ws_size >= wtBytes + 16 * perSplit) {
        // partial path, SPLIT=16 (SEGLEN=3136 = 49 x BK, grid 256)
        gemm_kernel<16, 3136, false><<<dim3(MT * 16), dim3(512), 0, stream>>>(labels, Wt, aux);
        reduce_norm_k<<<dim3(Mdim), dim3(320), 0, stream>>>(aux, out, 16);
    } else {
        // atomic fallback (needs 33.3 MB)
        hipMemsetAsync(aux, 0, perSplit, stream);
        gemm_kernel<49, 1024, true><<<dim3(MT * 49), dim3(512), 0, stream>>>(labels, Wt, aux);
        normalize_k<<<dim3(Mdim), dim3(320), 0, stream>>>(aux, out);
    }
}

// Round 4
// 401.672 us; speedup vs baseline: 1.8006x; 1.8006x over previous
//
#include <hip/hip_runtime.h>
#include <hip/hip_bf16.h>
#include <math.h>

// attr = labels(1024x50000 f32) @ weight(50000x300 f32); out = attr/(||attr||+1e-7)
// k1: weight -> Wt[n][k] bf16 (n padded to 320) -- LDS transpose
// k2: split-K MFMA GEMM, BM=64 BN=320 BK=64 (round-0 proven loop), with
//     (a) unpadded BKP=64 + XOR-swizzled LDS (T2) -> 48 KB -> 3 blocks/CU
//     (b) SPLIT=49 (grid 784) for latency-hiding TLP
//     (c) __launch_bounds__(512,4): VGPR cap 128 -- round 3's (512,6) forced
//         an 85-reg cap -> acc spilled to scratch (WRITE_SIZE 810 MB, 454 us).
//         Residency is LDS-bound at 3 blocks/CU regardless of the bound.
// k3: reduce partials over splits + row L2 normalize (fused)
typedef __bf16 bf16;
typedef bf16 bf16x8 __attribute__((ext_vector_type(8)));
typedef float f32x4 __attribute__((ext_vector_type(4)));

constexpr int Mdim = 1024;
constexpr int Kdim = 50000;
constexpr int Ndim = 300;
constexpr int NP   = 320;

constexpr int BM = 64, BN = 320, BK = 64;
constexpr int MT = Mdim / BM;      // 16 m-tiles
constexpr int ROWB = BK * 2;       // 128 B per LDS row (no pad; swizzled)

__device__ __forceinline__ bf16x8 bzero8() {
    bf16x8 v;
#pragma unroll
    for (int e = 0; e < 8; ++e) v[e] = (bf16)0.0f;
    return v;
}

// XOR swizzle: row-major [row][BK] bf16, byte_off ^= (row&7)<<4.
// All accesses are 16B-aligned; XOR flips bits 4..6 only -> stays aligned.
// Round-3 measured SQ_LDS_BANK_CONFLICT == 0 with this scheme.
__device__ __forceinline__ bf16* swz(bf16* base, int row, int colByte) {
    return (bf16*)((char*)base + row * ROWB + (colByte ^ ((row & 7) << 4)));
}
__device__ __forceinline__ const bf16* swz(const bf16* base, int row, int colByte) {
    return (const bf16*)((const char*)base + row * ROWB + (colByte ^ ((row & 7) << 4)));
}

// ---------------- k1: transpose + convert -----------------------------------
constexpr int TK = 64;
constexpr int TS = 301;
__global__ __launch_bounds__(256) void transpose_w(const float* __restrict__ W,
                                                   bf16* __restrict__ Wt)
{
    __shared__ bf16 tile[TK * TS];
    const int k0 = blockIdx.x * TK;
    const int t  = threadIdx.x;

    for (int c = t; c < 64 * 75; c += 256) {
        const int kk = c / 75;
        const int ch = c % 75;
        const int k  = k0 + kk;
        float4 v = make_float4(0.f, 0.f, 0.f, 0.f);
        if (k < Kdim) v = *(const float4*)(W + (size_t)k * Ndim + ch * 4);
        bf16* p = &tile[kk * TS + ch * 4];
        p[0] = (bf16)v.x; p[1] = (bf16)v.y; p[2] = (bf16)v.z; p[3] = (bf16)v.w;
    }
    __syncthreads();
    for (int c = t; c < NP * 8; c += 256) {
        const int n  = c >> 3;
        const int ch = c & 7;
        const int k  = k0 + ch * 8;
        if (k + 8 <= Kdim) {
            bf16x8 v = bzero8();
            if (n < Ndim) {
#pragma unroll
                for (int j = 0; j < 8; ++j) v[j] = tile[(ch * 8 + j) * TS + n];
            }
            *(bf16x8*)(Wt + (size_t)n * Kdim + k) = v;
        }
    }
}

// ---------------- k2: split-K MFMA GEMM (round-0 loop + swizzle + 3blk) -----
// ATOMIC=false: out = P, partials at P[ks][Mdim][NP] (plain stores)
// ATOMIC=true : out = Cacc[Mdim][NP] (atomicAdd), Cacc pre-zeroed
template<int SPLIT, int SEGLEN, bool ATOMIC>
__global__ __launch_bounds__(512, 4) void gemm_kernel(const float* __restrict__ A,
                                                      const bf16* __restrict__ Wt,
                                                      float* __restrict__ out)
{
    __shared__ bf16 As[BM * BK];   //  8192 B
    __shared__ bf16 Bs[BN * BK];   // 40960 B  (49152 total -> 3 blocks/CU)

    const int bx   = blockIdx.x;
    const int mt   = bx & (MT - 1);
    const int ks   = bx >> 4;
    const int m0   = mt * BM;
    const int kbeg = ks * SEGLEN;
    const int kend = min(kbeg + SEGLEN, Kdim);

    const int t    = threadIdx.x;
    const int lane = t & 63;
    const int wave = t >> 6;         // 0..7 as 2m x 4n
    const int wm   = wave >> 2;
    const int wn   = wave & 3;
    const int lm   = lane & 15;
    const int lq   = lane >> 4;      // 0..3

    const int arow = t >> 3;
    const int acol = (t & 7) * 8;    // elements
    const float* aptr = A + (size_t)(m0 + arow) * Kdim;

    float4 af[2];
    bf16x8 bfr[5];

    auto load_tiles = [&](int k0) {
        const int k = k0 + acol;
        if (k + 8 <= kend) {
            af[0] = *(const float4*)(aptr + k);
            af[1] = *(const float4*)(aptr + k + 4);
        } else {
            af[0] = make_float4(0.f, 0.f, 0.f, 0.f);
            af[1] = make_float4(0.f, 0.f, 0.f, 0.f);
        }
#pragma unroll
        for (int i = 0; i < 5; ++i) {
            const int c = t + 512 * i;
            const int brow = c >> 3;
            const int bcol = (c & 7) * 8;
            const int kk = k0 + bcol;
            bfr[i] = (kk + 8 <= kend) ? *(const bf16x8*)(Wt + (size_t)brow * Kdim + kk)
                                      : bzero8();
        }
    };
    auto store_tiles = [&]() {
        bf16x8 v;
        v[0]=(bf16)af[0].x; v[1]=(bf16)af[0].y; v[2]=(bf16)af[0].z; v[3]=(bf16)af[0].w;
        v[4]=(bf16)af[1].x; v[5]=(bf16)af[1].y; v[6]=(bf16)af[1].z; v[7]=(bf16)af[1].w;
        *(bf16x8*)swz(As, arow, acol * 2) = v;
#pragma unroll
        for (int i = 0; i < 5; ++i) {
            const int c = t + 512 * i;
            const int brow = c >> 3;
            const int bcol = (c & 7) * 8;
            *(bf16x8*)swz(Bs, brow, bcol * 2) = bfr[i];
        }
    };

    f32x4 acc[2][5] = {};

    load_tiles(kbeg);
    for (int k0 = kbeg; k0 < kend; k0 += BK) {
        store_tiles();
        __syncthreads();
        if (k0 + BK < kend) load_tiles(k0 + BK);
#pragma unroll
        for (int s = 0; s < 2; ++s) {
            bf16x8 a[2], b[5];
#pragma unroll
            for (int i = 0; i < 2; ++i)
                a[i] = *(const bf16x8*)swz(As, wm * 32 + i * 16 + lm, s * 64 + lq * 16);
#pragma unroll
            for (int j = 0; j < 5; ++j)
                b[j] = *(const bf16x8*)swz(Bs, wn * 80 + j * 16 + lm, s * 64 + lq * 16);
#pragma unroll
            for (int i = 0; i < 2; ++i)
#pragma unroll
                for (int j = 0; j < 5; ++j)
                    acc[i][j] = __builtin_amdgcn_mfma_f32_16x16x32_bf16(a[i], b[j], acc[i][j], 0, 0, 0);
        }
        __syncthreads();
    }

    // C/D layout: col=lane&15, row=(lane>>4)*4+r  [learn_hip m89]
    const int col0 = wn * 80 + lm;
    const int rloc = wm * 32 + lq * 4;
    if (ATOMIC) {
#pragma unroll
        for (int i = 0; i < 2; ++i)
#pragma unroll
            for (int j = 0; j < 5; ++j)
#pragma unroll
                for (int r = 0; r < 4; ++r)
                    atomicAdd(&out[(size_t)(m0 + rloc + i * 16 + r) * NP + col0 + j * 16],
                              acc[i][j][r]);
    } else {
        float* P = out + (size_t)ks * Mdim * NP;
#pragma unroll
        for (int i = 0; i < 2; ++i)
#pragma unroll
            for (int j = 0; j < 5; ++j)
#pragma unroll
                for (int r = 0; r < 4; ++r)
                    P[(size_t)(m0 + rloc + i * 16 + r) * NP + col0 + j * 16] = acc[i][j][r];
    }
}

// ---------------- k3a: reduce partials + L2 normalize (partial path) --------
__global__ __launch_bounds__(320) void reduce_norm_k(const float* __restrict__ P,
                                                     float* __restrict__ out,
                                                     int split)
{
    const int b = blockIdx.x;
    const int t = threadIdx.x;
    float v = 0.f;
    for (int ks = 0; ks < split; ++ks)
        v += P[((size_t)ks * Mdim + b) * NP + t];     // coalesced per ks
    float ss = v * v;
#pragma unroll
    for (int o = 32; o > 0; o >>= 1) ss += __shfl_down(ss, o, 64);
    __shared__ float wsum[5];
    __shared__ float scale;
    if ((t & 63) == 0) wsum[t >> 6] = ss;
    __syncthreads();
    if (t == 0) {
        float s = wsum[0] + wsum[1] + wsum[2] + wsum[3] + wsum[4];
        scale = 1.0f / (sqrtf(s) + 1e-7f);
    }
    __syncthreads();
    if (t < Ndim) out[(size_t)b * Ndim + t] = v * scale;
}

// ---------------- k3b: normalize only (atomic fallback path) ----------------
__global__ __launch_bounds__(320) void normalize_k(const float* __restrict__ Cacc,
                                                   float* __restrict__ out)
{
    const int b = blockIdx.x;
    const int t = threadIdx.x;
    float v = 0.f;
    if (t < Ndim) v = Cacc[(size_t)b * NP + t];
    float ss = v * v;
#pragma unroll
    for (int o = 32; o > 0; o >>= 1) ss += __shfl_down(ss, o, 64);
    __shared__ float wsum[5];
    __shared__ float scale;
    if ((t & 63) == 0) wsum[t >> 6] = ss;
    __syncthreads();
    if (t == 0) {
        float s = wsum[0] + wsum[1] + wsum[2] + wsum[3] + wsum[4];
        scale = 1.0f / (sqrtf(s) + 1e-7f);
    }
    __syncthreads();
    if (t < Ndim) out[(size_t)b * Ndim + t] = v * scale;
}

// ---------------- launch ----------------------------------------------------
extern "C" void kernel_launch(void* const* d_in, const int* in_sizes, int n_in,
                              void* d_out, int out_size, void* d_ws, size_t ws_size,
                              hipStream_t stream)
{
    const float* labels = (const float*)d_in[0];   // 1024 x 50000
    const float* weight = (const float*)d_in[1];   // 50000 x 300
    float* out = (float*)d_out;                    // 1024 x 300

    bf16* Wt = (bf16*)d_ws;                                   // 32.0 MB at offset 0
    const size_t wtBytes  = (size_t)NP * Kdim * sizeof(bf16); // 32,000,000
    float* aux = (float*)((char*)d_ws + wtBytes);
    const size_t perSplit = (size_t)Mdim * NP * sizeof(float); // 1.31 MB

    transpose_w<<<dim3((Kdim + TK - 1) / TK), dim3(256), 0, stream>>>(weight, Wt);

    if (ws_size >= wtBytes + 49 * perSplit) {
        // partial path, SPLIT=49 (SEGLEN=1024 = 16 x BK, grid 784 = 3.06 blk/CU)
        gemm_kernel<49, 1024, false><<<dim3(MT * 49), dim3(512), 0, stream>>>(labels, Wt, aux);
        reduce_norm_k<<<dim3(Mdim), dim3(320), 0, stream>>>(aux, out, 49);
    } else if (ws_size >= wtBytes + 16 * perSplit) {
        // partial path, SPLIT=16 (SEGLEN=3136 = 49 x BK, grid 256)
        gemm_kernel<16, 3136, false><<<dim3(MT * 16), dim3(512), 0, stream>>>(labels, Wt, aux);
        reduce_norm_k<<<dim3(Mdim), dim3(320), 0, stream>>>(aux, out, 16);
    } else {
        // atomic fallback (needs 33.3 MB)
        hipMemsetAsync(aux, 0, perSplit, stream);
        gemm_kernel<49, 1024, true><<<dim3(MT * 49), dim3(512), 0, stream>>>(labels, Wt, aux);
        normalize_k<<<dim3(Mdim), dim3(320), 0, stream>>>(aux, out);
    }
}

// Round 5
// 378.103 us; speedup vs baseline: 1.9128x; 1.0623x over previous
//
#include <hip/hip_runtime.h>
#include <hip/hip_bf16.h>
#include <math.h>

// attr = labels(1024x50000 f32) @ weight(50000x300 f32); out = attr/(||attr||+1e-7)
// k1: weight -> Wt[n][k] bf16, n padded to 320, k padded to 50048 (zeros) --
//     pad makes every gemm B-DMA in-bounds and zero-contributing past Kdim.
// k2: split-K MFMA GEMM, BM=64 BN=320 BK=64, 48 KB LDS (3 blocks/CU):
//     B staged via global_load_lds width-16 DMA (no VGPR roundtrip, no ds_write)
//       with inverse-swizzled GLOBAL source + linear LDS dest (rule #21);
//     A staged via regs (f32->bf16 convert) + 1 swizzled ds_write_b128/thread.
//     Round-4 measured conflicts == 0 with this XOR scheme.
// k3: reduce partials over splits + row L2 normalize (fused)
typedef __bf16 bf16;
typedef bf16 bf16x8 __attribute__((ext_vector_type(8)));
typedef float f32x4 __attribute__((ext_vector_type(4)));

constexpr int Mdim = 1024;
constexpr int Kdim = 50000;
constexpr int Kpad = 50048;        // 782*64; >= kbeg + ceil(seg/64)*64 for all splits
constexpr int Ndim = 300;
constexpr int NP   = 320;

constexpr int BM = 64, BN = 320, BK = 64;
constexpr int MT = Mdim / BM;      // 16 m-tiles
constexpr int ROWB = BK * 2;       // 128 B per LDS row (no pad; swizzled)

__device__ __forceinline__ bf16x8 bzero8() {
    bf16x8 v;
#pragma unroll
    for (int e = 0; e < 8; ++e) v[e] = (bf16)0.0f;
    return v;
}

// XOR swizzle: row-major [row][BK] bf16, byte_off ^= (row&7)<<4.
// 16B-aligned accesses only; XOR flips bits 4..6 -> alignment preserved.
__device__ __forceinline__ bf16* swz(bf16* base, int row, int colByte) {
    return (bf16*)((char*)base + row * ROWB + (colByte ^ ((row & 7) << 4)));
}
__device__ __forceinline__ const bf16* swz(const bf16* base, int row, int colByte) {
    return (const bf16*)((const char*)base + row * ROWB + (colByte ^ ((row & 7) << 4)));
}

// width-16 global->LDS DMA. LDS dest must be WAVE-UNIFORM base (HW adds lane*16);
// global src is per-lane.
__device__ __forceinline__ void dma16(const void* g, void* l) {
    __builtin_amdgcn_global_load_lds(
        (const __attribute__((address_space(1))) unsigned int*)g,
        (__attribute__((address_space(3))) unsigned int*)l, 16, 0, 0);
}

// ---------------- k1: transpose + convert (k-padded to Kpad) ----------------
constexpr int TK = 64;
constexpr int TS = 301;
__global__ __launch_bounds__(256) void transpose_w(const float* __restrict__ W,
                                                   bf16* __restrict__ Wt)
{
    __shared__ bf16 tile[TK * TS];
    const int k0 = blockIdx.x * TK;
    const int t  = threadIdx.x;

    for (int c = t; c < 64 * 75; c += 256) {
        const int kk = c / 75;
        const int ch = c % 75;
        const int k  = k0 + kk;
        float4 v = make_float4(0.f, 0.f, 0.f, 0.f);
        if (k < Kdim) v = *(const float4*)(W + (size_t)k * Ndim + ch * 4);
        bf16* p = &tile[kk * TS + ch * 4];
        p[0] = (bf16)v.x; p[1] = (bf16)v.y; p[2] = (bf16)v.z; p[3] = (bf16)v.w;
    }
    __syncthreads();
    for (int c = t; c < NP * 8; c += 256) {
        const int n  = c >> 3;
        const int ch = c & 7;
        const int k  = k0 + ch * 8;     // k+8 <= Kpad always (grid covers Kpad)
        bf16x8 v = bzero8();
        if (n < Ndim) {
#pragma unroll
            for (int j = 0; j < 8; ++j)
                v[j] = tile[(ch * 8 + j) * TS + n];   // zeros if k>=Kdim (tile zero-filled)
        }
        *(bf16x8*)(Wt + (size_t)n * Kpad + k) = v;
    }
}

// ---------------- k2: split-K MFMA GEMM (B via global_load_lds) -------------
// ATOMIC=false: out = P, partials at P[ks][Mdim][NP] (plain stores)
// ATOMIC=true : out = Cacc[Mdim][NP] (atomicAdd), Cacc pre-zeroed
template<int SPLIT, int SEGLEN, bool ATOMIC>
__global__ __launch_bounds__(512, 4) void gemm_kernel(const float* __restrict__ A,
                                                      const bf16* __restrict__ Wt,
                                                      float* __restrict__ out)
{
    __shared__ bf16 As[BM * BK];   //  8192 B
    __shared__ bf16 Bs[BN * BK];   // 40960 B  (49152 total -> 3 blocks/CU)

    const int bx   = blockIdx.x;
    const int mt   = bx & (MT - 1);
    const int ks   = bx >> 4;
    const int m0   = mt * BM;
    const int kbeg = ks * SEGLEN;
    const int kend = min(kbeg + SEGLEN, Kdim);

    const int t    = threadIdx.x;
    const int lane = t & 63;
    const int wave = t >> 6;         // 0..7 as 2m x 4n
    const int wm   = wave >> 2;
    const int wn   = wave & 3;
    const int lm   = lane & 15;
    const int lq   = lane >> 4;      // 0..3

    // ---- A reg staging (convert path) ----
    const int arow = t >> 3;
    const int acol = (t & 7) * 8;    // elements; kend is a multiple of 8 per split
    const float* aptr = A + (size_t)(m0 + arow) * Kdim;
    float4 af[2];

    auto loadA = [&](int k0) {
        const int k = k0 + acol;
        if (k + 8 <= kend) {
            af[0] = *(const float4*)(aptr + k);
            af[1] = *(const float4*)(aptr + k + 4);
        } else {
            af[0] = make_float4(0.f, 0.f, 0.f, 0.f);
            af[1] = make_float4(0.f, 0.f, 0.f, 0.f);
        }
    };
    auto storeA = [&]() {
        bf16x8 v;
        v[0]=(bf16)af[0].x; v[1]=(bf16)af[0].y; v[2]=(bf16)af[0].z; v[3]=(bf16)af[0].w;
        v[4]=(bf16)af[1].x; v[5]=(bf16)af[1].y; v[6]=(bf16)af[1].z; v[7]=(bf16)af[1].w;
        *(bf16x8*)swz(As, arow, acol * 2) = v;
    };

    // ---- B DMA staging: 40 x 1 KiB chunks; wave w owns chunks 5w..5w+4 ----
    // LDS slot (row, colByte=(lane&7)*16)  <-  global col ((lane&7)^(lane>>3))*16
    // (inverse of the read-side XOR; row&7 == lane>>3 inside each 1 KiB chunk)
    const int r8   = lane >> 3;                       // 0..7
    const int cswz = ((lane & 7) ^ r8) * 16;          // source byte offset in row
    auto stageB = [&](int k0) {
#pragma unroll
        for (int i = 0; i < 5; ++i) {
            const int chunk = wave * 5 + i;           // 0..39
            const int row   = chunk * 8 + r8;         // 0..319
            const char* g = (const char*)Wt + ((size_t)row * Kpad + k0) * 2 + cswz;
            dma16(g, (char*)Bs + chunk * 1024);       // uniform base; HW adds lane*16
        }
    };

    f32x4 acc[2][5] = {};

    loadA(kbeg);
    for (int k0 = kbeg; k0 < kend; k0 += BK) {
        __syncthreads();                 // prev step's LDS reads complete
        stageB(k0);                      // async DMA into Bs
        storeA();                        // convert + 1 ds_write_b128
        if (k0 + BK < kend) loadA(k0 + BK);   // next-A regs; drains with the DMA
        __syncthreads();                 // vmcnt(0)+lgkm drain: Bs/As ready
#pragma unroll
        for (int s = 0; s < 2; ++s) {
            bf16x8 a[2], b[5];
#pragma unroll
            for (int i = 0; i < 2; ++i)
                a[i] = *(const bf16x8*)swz(As, wm * 32 + i * 16 + lm, s * 64 + lq * 16);
#pragma unroll
            for (int j = 0; j < 5; ++j)
                b[j] = *(const bf16x8*)swz(Bs, wn * 80 + j * 16 + lm, s * 64 + lq * 16);
#pragma unroll
            for (int i = 0; i < 2; ++i)
#pragma unroll
                for (int j = 0; j < 5; ++j)
                    acc[i][j] = __builtin_amdgcn_mfma_f32_16x16x32_bf16(a[i], b[j], acc[i][j], 0, 0, 0);
        }
    }

    // C/D layout: col=lane&15, row=(lane>>4)*4+r  [learn_hip m89]
    const int col0 = wn * 80 + lm;
    const int rloc = wm * 32 + lq * 4;
    if (ATOMIC) {
#pragma unroll
        for (int i = 0; i < 2; ++i)
#pragma unroll
            for (int j = 0; j < 5; ++j)
#pragma unroll
                for (int r = 0; r < 4; ++r)
                    atomicAdd(&out[(size_t)(m0 + rloc + i * 16 + r) * NP + col0 + j * 16],
                              acc[i][j][r]);
    } else {
        float* P = out + (size_t)ks * Mdim * NP;
#pragma unroll
        for (int i = 0; i < 2; ++i)
#pragma unroll
            for (int j = 0; j < 5; ++j)
#pragma unroll
                for (int r = 0; r < 4; ++r)
                    P[(size_t)(m0 + rloc + i * 16 + r) * NP + col0 + j * 16] = acc[i][j][r];
    }
}

// ---------------- k3a: reduce partials + L2 normalize (partial path) --------
__global__ __launch_bounds__(320) void reduce_norm_k(const float* __restrict__ P,
                                                     float* __restrict__ out,
                                                     int split)
{
    const int b = blockIdx.x;
    const int t = threadIdx.x;
    float v = 0.f;
    for (int ks = 0; ks < split; ++ks)
        v += P[((size_t)ks * Mdim + b) * NP + t];     // coalesced per ks
    float ss = v * v;
#pragma unroll
    for (int o = 32; o > 0; o >>= 1) ss += __shfl_down(ss, o, 64);
    __shared__ float wsum[5];
    __shared__ float scale;
    if ((t & 63) == 0) wsum[t >> 6] = ss;
    __syncthreads();
    if (t == 0) {
        float s = wsum[0] + wsum[1] + wsum[2] + wsum[3] + wsum[4];
        scale = 1.0f / (sqrtf(s) + 1e-7f);
    }
    __syncthreads();
    if (t < Ndim) out[(size_t)b * Ndim + t] = v * scale;
}

// ---------------- k3b: normalize only (atomic fallback path) ----------------
__global__ __launch_bounds__(320) void normalize_k(const float* __restrict__ Cacc,
                                                   float* __restrict__ out)
{
    const int b = blockIdx.x;
    const int t = threadIdx.x;
    float v = 0.f;
    if (t < Ndim) v = Cacc[(size_t)b * NP + t];
    float ss = v * v;
#pragma unroll
    for (int o = 32; o > 0; o >>= 1) ss += __shfl_down(ss, o, 64);
    __shared__ float wsum[5];
    __shared__ float scale;
    if ((t & 63) == 0) wsum[t >> 6] = ss;
    __syncthreads();
    if (t == 0) {
        float s = wsum[0] + wsum[1] + wsum[2] + wsum[3] + wsum[4];
        scale = 1.0f / (sqrtf(s) + 1e-7f);
    }
    __syncthreads();
    if (t < Ndim) out[(size_t)b * Ndim + t] = v * scale;
}

// ---------------- launch ----------------------------------------------------
extern "C" void kernel_launch(void* const* d_in, const int* in_sizes, int n_in,
                              void* d_out, int out_size, void* d_ws, size_t ws_size,
                              hipStream_t stream)
{
    const float* labels = (const float*)d_in[0];   // 1024 x 50000
    const float* weight = (const float*)d_in[1];   // 50000 x 300
    float* out = (float*)d_out;                    // 1024 x 300

    bf16* Wt = (bf16*)d_ws;                                   // 32.03 MB at offset 0
    const size_t wtBytes  = (size_t)NP * Kpad * sizeof(bf16); // 32,030,720
    float* aux = (float*)((char*)d_ws + wtBytes);
    const size_t perSplit = (size_t)Mdim * NP * sizeof(float); // 1.31 MB

    transpose_w<<<dim3(Kpad / TK), dim3(256), 0, stream>>>(weight, Wt);

    if (ws_size >= wtBytes + 49 * perSplit) {
        // partial path, SPLIT=49 (SEGLEN=1024 = 16 x BK, grid 784 = 3.06 blk/CU)
        gemm_kernel<49, 1024, false><<<dim3(MT * 49), dim3(512), 0, stream>>>(labels, Wt, aux);
        reduce_norm_k<<<dim3(Mdim), dim3(320), 0, stream>>>(aux, out, 49);
    } else if (ws_size >= wtBytes + 16 * perSplit) {
        // partial path, SPLIT=16 (SEGLEN=3136 = 49 x BK, grid 256)
        gemm_kernel<16, 3136, false><<<dim3(MT * 16), dim3(512), 0, stream>>>(labels, Wt, aux);
        reduce_norm_k<<<dim3(Mdim), dim3(320), 0, stream>>>(aux, out, 16);
    } else {
        // atomic fallback (needs ~33.4 MB)
        hipMemsetAsync(aux, 0, perSplit, stream);
        gemm_kernel<49, 1024, true><<<dim3(MT * 49), dim3(512), 0, stream>>>(labels, Wt, aux);
        normalize_k<<<dim3(Mdim), dim3(320), 0, stream>>>(aux, out);
    }
}

// Round 6
// 371.764 us; speedup vs baseline: 1.9454x; 1.0171x over previous
//
#include <hip/hip_runtime.h>
#include <hip/hip_bf16.h>
#include <math.h>

// attr = labels(1024x50000 f32) @ weight(50000x300 f32); out = attr/(||attr||+1e-7)
// k1: weight -> Wt[n][k] bf16, n padded to 320, k padded to 50048 (zeros).
// k2: split-K MFMA GEMM, BM=64 BN=320 BK=64, DOUBLE-BUFFERED 96 KB LDS,
//     distance-1 DMA prefetch + ONE raw s_barrier per step with COUNTED
//     s_waitcnt vmcnt(2): the 5 B-DMAs (issued a full step early) drain
//     after a whole compute phase of cover; the 2 A-loads stay in flight
//     across the barrier. A reads use clamped addresses (past-kend reads
//     hit valid A floats x zero-padded B => contribute 0, no NaN).
//     SPLIT=48 grid 768 = 3x256; XCD-bijective block map co-locates the
//     16 same-ks blocks (shared Wt slice) on one XCD's L2.
// k3: reduce partials over splits + row L2 normalize (fused)
typedef __bf16 bf16;
typedef bf16 bf16x8 __attribute__((ext_vector_type(8)));
typedef float f32x4 __attribute__((ext_vector_type(4)));

constexpr int Mdim = 1024;
constexpr int Kdim = 50000;
constexpr int Kpad = 50048;        // 782*64; covers last step k0=49984 (+64)
constexpr int Ndim = 300;
constexpr int NP   = 320;

constexpr int BM = 64, BN = 320, BK = 64;
constexpr int MT = Mdim / BM;      // 16 m-tiles
constexpr int ROWB = BK * 2;       // 128 B per LDS row (no pad; swizzled)

__device__ __forceinline__ bf16x8 bzero8() {
    bf16x8 v;
#pragma unroll
    for (int e = 0; e < 8; ++e) v[e] = (bf16)0.0f;
    return v;
}

// XOR swizzle: row-major [row][BK] bf16, byte_off ^= (row&7)<<4.
// 16B-aligned accesses only; XOR flips bits 4..6 -> alignment preserved.
// Rounds 3-5 measured SQ_LDS_BANK_CONFLICT == 0 with this scheme.
__device__ __forceinline__ bf16* swz(bf16* base, int row, int colByte) {
    return (bf16*)((char*)base + row * ROWB + (colByte ^ ((row & 7) << 4)));
}
__device__ __forceinline__ const bf16* swz(const bf16* base, int row, int colByte) {
    return (const bf16*)((const char*)base + row * ROWB + (colByte ^ ((row & 7) << 4)));
}

// width-16 global->LDS DMA. LDS dest is wave-uniform base (HW adds lane*16);
// global src is per-lane.
__device__ __forceinline__ void dma16(const void* g, void* l) {
    __builtin_amdgcn_global_load_lds(
        (const __attribute__((address_space(1))) unsigned int*)g,
        (__attribute__((address_space(3))) unsigned int*)l, 16, 0, 0);
}

// ---------------- k1: transpose + convert (k-padded to Kpad) ----------------
constexpr int TK = 64;
constexpr int TS = 301;
__global__ __launch_bounds__(256) void transpose_w(const float* __restrict__ W,
                                                   bf16* __restrict__ Wt)
{
    __shared__ bf16 tile[TK * TS];
    const int k0 = blockIdx.x * TK;
    const int t  = threadIdx.x;

    for (int c = t; c < 64 * 75; c += 256) {
        const int kk = c / 75;
        const int ch = c % 75;
        const int k  = k0 + kk;
        float4 v = make_float4(0.f, 0.f, 0.f, 0.f);
        if (k < Kdim) v = *(const float4*)(W + (size_t)k * Ndim + ch * 4);
        bf16* p = &tile[kk * TS + ch * 4];
        p[0] = (bf16)v.x; p[1] = (bf16)v.y; p[2] = (bf16)v.z; p[3] = (bf16)v.w;
    }
    __syncthreads();
    for (int c = t; c < NP * 8; c += 256) {
        const int n  = c >> 3;
        const int ch = c & 7;
        const int k  = k0 + ch * 8;     // k+8 <= Kpad always (grid covers Kpad)
        bf16x8 v = bzero8();
        if (n < Ndim) {
#pragma unroll
            for (int j = 0; j < 8; ++j)
                v[j] = tile[(ch * 8 + j) * TS + n];   // zeros if k>=Kdim
        }
        *(bf16x8*)(Wt + (size_t)n * Kpad + k) = v;
    }
}

// ---------------- k2: split-K MFMA GEMM (dbuf + counted-vmcnt pipeline) -----
// ATOMIC=false: out = P, partials at P[ks][Mdim][NP] (plain stores)
// ATOMIC=true : out = Cacc[Mdim][NP] (atomicAdd), Cacc pre-zeroed
template<int SPLIT, int SEGLEN, bool ATOMIC>
__global__ __launch_bounds__(512, 2) void gemm_kernel(const float* __restrict__ A,
                                                      const bf16* __restrict__ Wt,
                                                      float* __restrict__ out)
{
    __shared__ bf16 As[2][BM * BK];   // 2 x  8192 B
    __shared__ bf16 Bs[2][BN * BK];   // 2 x 40960 B  (98304 total -> 1 block/CU)

    const int bx = blockIdx.x;
    int mt, ks;
    if (SPLIT == 48) {
        // XCD-bijective (grid 768 = 8 XCD x 96): XCD x gets ks in [6x, 6x+6),
        // all 16 m-tiles of a ks on the same XCD -> Wt slice fetched once/L2.
        const int x = bx & 7;            // dispatch round-robins XCDs [m09]
        const int i = bx >> 3;           // 0..95
        ks = x * 6 + (i >> 4);
        mt = i & 15;
    } else {
        mt = bx & (MT - 1);
        ks = bx >> 4;
    }
    const int m0   = mt * BM;
    const int kbeg = ks * SEGLEN;
    const int kend = min(kbeg + SEGLEN, Kdim);

    const int t    = threadIdx.x;
    const int lane = t & 63;
    const int wave = t >> 6;         // 0..7 as 2m x 4n
    const int wm   = wave >> 2;
    const int wn   = wave & 3;
    const int lm   = lane & 15;
    const int lq   = lane >> 4;      // 0..3

    // ---- A reg staging (convert path), clamped unconditional loads ----
    const int arow = t >> 3;
    const int acol = (t & 7) * 8;    // elements
    const size_t alim  = (size_t)Mdim * Kdim - 8;
    const size_t abase = (size_t)(m0 + arow) * Kdim + acol;
    float4 af[2];

    auto loadA = [&](int k0) {
        size_t off = abase + (size_t)k0;
        if (off > alim) off = alim;          // stays in A; garbage x B==0 -> 0
        const float* p = A + off;
        af[0] = *(const float4*)p;
        af[1] = *(const float4*)(p + 4);
    };
    auto storeA = [&](int buf) {
        bf16x8 v;
        v[0]=(bf16)af[0].x; v[1]=(bf16)af[0].y; v[2]=(bf16)af[0].z; v[3]=(bf16)af[0].w;
        v[4]=(bf16)af[1].x; v[5]=(bf16)af[1].y; v[6]=(bf16)af[1].z; v[7]=(bf16)af[1].w;
        *(bf16x8*)swz(As[buf], arow, acol * 2) = v;
    };

    // ---- B DMA staging: 40 x 1 KiB chunks; wave w owns chunks 5w..5w+4 ----
    // LDS slot (row, colByte=(lane&7)*16)  <-  global col ((lane&7)^(lane>>3))*16
    const int r8   = lane >> 3;                       // 0..7
    const int cswz = ((lane & 7) ^ r8) * 16;          // inverse of read-side XOR
    auto stageB = [&](int k0, int buf) {
#pragma unroll
        for (int i = 0; i < 5; ++i) {
            const int chunk = wave * 5 + i;           // 0..39
            const int row   = chunk * 8 + r8;         // 0..319
            const char* g = (const char*)Wt + ((size_t)row * Kpad + k0) * 2 + cswz;
            dma16(g, (char*)Bs[buf] + chunk * 1024);  // uniform base per wave
        }
    };

    f32x4 acc[2][5] = {};

    auto compute = [&](int buf) {
#pragma unroll
        for (int s = 0; s < 2; ++s) {
            bf16x8 a[2], b[5];
#pragma unroll
            for (int i = 0; i < 2; ++i)
                a[i] = *(const bf16x8*)swz(As[buf], wm * 32 + i * 16 + lm, s * 64 + lq * 16);
#pragma unroll
            for (int j = 0; j < 5; ++j)
                b[j] = *(const bf16x8*)swz(Bs[buf], wn * 80 + j * 16 + lm, s * 64 + lq * 16);
#pragma unroll
            for (int i = 0; i < 2; ++i)
#pragma unroll
                for (int j = 0; j < 5; ++j)
                    acc[i][j] = __builtin_amdgcn_mfma_f32_16x16x32_bf16(a[i], b[j], acc[i][j], 0, 0, 0);
        }
    };

    if (kbeg < kend) {
        // ---- prologue: stage step 0, prefetch step-1 A regs ----
        loadA(kbeg);
        stageB(kbeg, 0);
        storeA(0);                       // compiler waits the 2 A-loads (vmcnt(5))
        loadA(kbeg + BK);                // clamped; harmless if single-step seg
        __builtin_amdgcn_sched_barrier(0);
        asm volatile("s_waitcnt vmcnt(2) lgkmcnt(0)" ::: "memory"); // drain 5 DMAs
        __builtin_amdgcn_s_barrier();
        __builtin_amdgcn_sched_barrier(0);

        int cur = 0;
        int k0  = kbeg;
        for (; k0 + BK < kend; k0 += BK) {
            const int nb = cur ^ 1;
            stageB(k0 + BK, nb);                      // 5 DMAs, oldest in queue
            __builtin_amdgcn_sched_barrier(0);
            storeA(nb);                               // af = A(k0+BK); ds_write
            const bool more2 = (k0 + 2 * BK < kend);
            if (more2) loadA(k0 + 2 * BK);            // 2 loads, newest in queue
            compute(cur);
            __builtin_amdgcn_sched_barrier(0);
            if (more2) asm volatile("s_waitcnt vmcnt(2) lgkmcnt(0)" ::: "memory");
            else       asm volatile("s_waitcnt vmcnt(0) lgkmcnt(0)" ::: "memory");
            __builtin_amdgcn_s_barrier();
            __builtin_amdgcn_sched_barrier(0);
            cur = nb;
        }
        compute(cur);                                 // final step, no staging
    }

    // C/D layout: col=lane&15, row=(lane>>4)*4+r  [learn_hip m89]
    const int col0 = wn * 80 + lm;
    const int rloc = wm * 32 + lq * 4;
    if (ATOMIC) {
#pragma unroll
        for (int i = 0; i < 2; ++i)
#pragma unroll
            for (int j = 0; j < 5; ++j)
#pragma unroll
                for (int r = 0; r < 4; ++r)
                    atomicAdd(&out[(size_t)(m0 + rloc + i * 16 + r) * NP + col0 + j * 16],
                              acc[i][j][r]);
    } else {
        float* P = out + (size_t)ks * Mdim * NP;
#pragma unroll
        for (int i = 0; i < 2; ++i)
#pragma unroll
            for (int j = 0; j < 5; ++j)
#pragma unroll
                for (int r = 0; r < 4; ++r)
                    P[(size_t)(m0 + rloc + i * 16 + r) * NP + col0 + j * 16] = acc[i][j][r];
    }
}

// ---------------- k3a: reduce partials + L2 normalize (partial path) --------
__global__ __launch_bounds__(320) void reduce_norm_k(const float* __restrict__ P,
                                                     float* __restrict__ out,
                                                     int split)
{
    const int b = blockIdx.x;
    const int t = threadIdx.x;
    float v = 0.f;
    for (int ks = 0; ks < split; ++ks)
        v += P[((size_t)ks * Mdim + b) * NP + t];     // coalesced per ks
    float ss = v * v;
#pragma unroll
    for (int o = 32; o > 0; o >>= 1) ss += __shfl_down(ss, o, 64);
    __shared__ float wsum[5];
    __shared__ float scale;
    if ((t & 63) == 0) wsum[t >> 6] = ss;
    __syncthreads();
    if (t == 0) {
        float s = wsum[0] + wsum[1] + wsum[2] + wsum[3] + wsum[4];
        scale = 1.0f / (sqrtf(s) + 1e-7f);
    }
    __syncthreads();
    if (t < Ndim) out[(size_t)b * Ndim + t] = v * scale;
}

// ---------------- k3b: normalize only (atomic fallback path) ----------------
__global__ __launch_bounds__(320) void normalize_k(const float* __restrict__ Cacc,
                                                   float* __restrict__ out)
{
    const int b = blockIdx.x;
    const int t = threadIdx.x;
    float v = 0.f;
    if (t < Ndim) v = Cacc[(size_t)b * NP + t];
    float ss = v * v;
#pragma unroll
    for (int o = 32; o > 0; o >>= 1) ss += __shfl_down(ss, o, 64);
    __shared__ float wsum[5];
    __shared__ float scale;
    if ((t & 63) == 0) wsum[t >> 6] = ss;
    __syncthreads();
    if (t == 0) {
        float s = wsum[0] + wsum[1] + wsum[2] + wsum[3] + wsum[4];
        scale = 1.0f / (sqrtf(s) + 1e-7f);
    }
    __syncthreads();
    if (t < Ndim) out[(size_t)b * Ndim + t] = v * scale;
}

// ---------------- launch ----------------------------------------------------
extern "C" void kernel_launch(void* const* d_in, const int* in_sizes, int n_in,
                              void* d_out, int out_size, void* d_ws, size_t ws_size,
                              hipStream_t stream)
{
    const float* labels = (const float*)d_in[0];   // 1024 x 50000
    const float* weight = (const float*)d_in[1];   // 50000 x 300
    float* out = (float*)d_out;                    // 1024 x 300

    bf16* Wt = (bf16*)d_ws;                                   // 32.03 MB at offset 0
    const size_t wtBytes  = (size_t)NP * Kpad * sizeof(bf16); // 32,030,720
    float* aux = (float*)((char*)d_ws + wtBytes);
    const size_t perSplit = (size_t)Mdim * NP * sizeof(float); // 1.31 MB

    transpose_w<<<dim3(Kpad / TK), dim3(256), 0, stream>>>(weight, Wt);

    if (ws_size >= wtBytes + 48 * perSplit) {
        // SPLIT=48, SEGLEN=1088=17xBK, grid 768=3x256 (ks 46,47 empty -> zeros)
        gemm_kernel<48, 1088, false><<<dim3(MT * 48), dim3(512), 0, stream>>>(labels, Wt, aux);
        reduce_norm_k<<<dim3(Mdim), dim3(320), 0, stream>>>(aux, out, 48);
    } else if (ws_size >= wtBytes + 16 * perSplit) {
        // SPLIT=16, SEGLEN=3200=50xBK, grid 256
        gemm_kernel<16, 3200, false><<<dim3(MT * 16), dim3(512), 0, stream>>>(labels, Wt, aux);
        reduce_norm_k<<<dim3(Mdim), dim3(320), 0, stream>>>(aux, out, 16);
    } else {
        // atomic fallback (needs ~33.4 MB)
        hipMemsetAsync(aux, 0, perSplit, stream);
        gemm_kernel<48, 1088, true><<<dim3(MT * 48), dim3(512), 0, stream>>>(labels, Wt, aux);
        normalize_k<<<dim3(Mdim), dim3(320), 0, stream>>>(aux, out);
    }
}